// Round 3
// baseline (973.102 us; speedup 1.0000x reference)
//
#include <hip/hip_runtime.h>
#include <math.h>

#define F_IN   128
#define F_OUT  64
#define CHUNK  8192          // edges per pass-A/B block
#define MAXB   512           // max coarse buckets (N/256 <= 512)

__device__ __forceinline__ float bf2f(unsigned short u) {
    union { unsigned int i; float f; } c; c.i = ((unsigned int)u) << 16; return c.f;
}
__device__ __forceinline__ unsigned short f2bf(float f) {
    union { float f; unsigned int i; } c; c.f = f;
    unsigned int r = c.i + 0x7FFFu + ((c.i >> 16) & 1u);   // RNE
    return (unsigned short)(r >> 16);
}

// ---- pass A: per-block coarse histogram [bucket][block] + global in-degree count ----
__global__ __launch_bounds__(256) void k_hist(
    const int* __restrict__ dst, int E, int* __restrict__ cnt,
    int* __restrict__ M, int NBLK, int NBC) {
    __shared__ int hist[MAXB];
    for (int c = threadIdx.x; c < MAXB; c += 256) hist[c] = 0;
    __syncthreads();
    int e0 = blockIdx.x * CHUNK;
    int e1 = min(E, e0 + CHUNK);
    for (int e = e0 + threadIdx.x; e < e1; e += 256) {
        int d = dst[e];
        atomicAdd(&cnt[d], 1);
        atomicAdd(&hist[d >> 8], 1);
    }
    __syncthreads();
    for (int c = threadIdx.x; c < NBC; c += 256)
        M[c * NBLK + blockIdx.x] = hist[c];
}

// ---- flat exclusive scan over S = NBC*NBLK elements (3 phases) ----
__global__ void k_scan1(const int* __restrict__ M, int* __restrict__ tmp,
                        int* __restrict__ bsum, int S) {
    __shared__ int sh[256];
    int i = blockIdx.x * 256 + threadIdx.x;
    int v = (i < S) ? M[i] : 0;
    sh[threadIdx.x] = v;
    __syncthreads();
    for (int off = 1; off < 256; off <<= 1) {
        int t = (threadIdx.x >= off) ? sh[threadIdx.x - off] : 0;
        __syncthreads();
        sh[threadIdx.x] += t;
        __syncthreads();
    }
    if (i < S) tmp[i] = sh[threadIdx.x];
    if (threadIdx.x == 255) bsum[blockIdx.x] = sh[255];
}

__global__ void k_scan2(int* __restrict__ bsum, int NB1) {
    __shared__ int sh[512];
    int v = (threadIdx.x < NB1) ? bsum[threadIdx.x] : 0;
    sh[threadIdx.x] = v;
    __syncthreads();
    for (int off = 1; off < 512; off <<= 1) {
        int t = (threadIdx.x >= off) ? sh[threadIdx.x - off] : 0;
        __syncthreads();
        sh[threadIdx.x] += t;
        __syncthreads();
    }
    if (threadIdx.x < NB1) bsum[threadIdx.x] = sh[threadIdx.x] - v;   // exclusive
}

// scan3: M <- exclusive scan; also extract coarseOff[bucket] = scan at column 0
__global__ void k_scan3(int* __restrict__ M, const int* __restrict__ tmp,
                        const int* __restrict__ bsum, int* __restrict__ coarseOff,
                        int S, int NBLK, int NBC, int E) {
    int i = blockIdx.x * 256 + threadIdx.x;
    if (i < S) {
        int orig = M[i];
        int o = tmp[i] - orig + bsum[blockIdx.x];
        M[i] = o;
        if (i % NBLK == 0) coarseOff[i / NBLK] = o;
    }
    if (i == 0) coarseOff[NBC] = E;
}

// ---- pass B: scatter packed entries (localdst<<24 | src) into coarse buckets ----
__global__ __launch_bounds__(256) void k_scatter(
    const int* __restrict__ src, const int* __restrict__ dst, int E,
    const int* __restrict__ M, int NBLK, int NBC, unsigned int* __restrict__ entries) {
    __shared__ int cur[MAXB];
    for (int c = threadIdx.x; c < NBC; c += 256)
        cur[c] = M[c * NBLK + blockIdx.x];
    __syncthreads();
    int e0 = blockIdx.x * CHUNK;
    int e1 = min(E, e0 + CHUNK);
    for (int e = e0 + threadIdx.x; e < e1; e += 256) {
        int d = dst[e];
        int s = src[e];
        int p = atomicAdd(&cur[d >> 8], 1);
        entries[p] = ((unsigned int)(d & 255) << 24) | (unsigned int)s;
    }
}

// ---- g = bf16( (x @ W^T) * rsqrt(cnt[row]+1) ) ----
__global__ __launch_bounds__(256) void k_gemm(
    const float* __restrict__ x, const float* __restrict__ W,
    const int* __restrict__ cnt, unsigned short* __restrict__ g, int N) {
    __shared__ float Ws[F_OUT * F_IN];   // swizzled, 32 KB
    __shared__ float xs[16 * F_IN];      // 8 KB

    const int tid = threadIdx.x;
    const int f   = tid & 63;
    const int rg  = tid >> 6;

    const float4* W4 = (const float4*)W;
    float4* Ws4 = (float4*)Ws;
    {
        int idx4 = tid;
        #pragma unroll
        for (int t = 0; t < 8; ++t, idx4 += 256) {
            int fr = idx4 >> 5;
            int q  = idx4 & 31;
            Ws4[fr * 32 + (q ^ (fr & 31))] = W4[idx4];
        }
    }

    const int row0 = blockIdx.x * 64;
    float4* xs4 = (float4*)xs;

    for (int c = 0; c < 4; ++c) {
        int rbase = row0 + c * 16;
        __syncthreads();
        {
            const float4* x4 = (const float4*)x;
            int idx4 = tid;
            #pragma unroll
            for (int t = 0; t < 2; ++t, idx4 += 256) {
                int r  = idx4 >> 5;
                int cq = idx4 & 31;
                int grow = rbase + r;
                float4 v = make_float4(0.f, 0.f, 0.f, 0.f);
                if (grow < N) v = x4[(size_t)grow * 32 + cq];
                xs4[r * 32 + cq] = v;
            }
        }
        __syncthreads();

        float acc0 = 0.f, acc1 = 0.f, acc2 = 0.f, acc3 = 0.f;
        const int xbase = rg * 4;
        #pragma unroll 4
        for (int q = 0; q < 32; ++q) {
            float4 w = Ws4[f * 32 + (q ^ (f & 31))];
            float4 a0 = xs4[(xbase + 0) * 32 + q];
            float4 a1 = xs4[(xbase + 1) * 32 + q];
            float4 a2 = xs4[(xbase + 2) * 32 + q];
            float4 a3 = xs4[(xbase + 3) * 32 + q];
            acc0 = fmaf(a0.x, w.x, fmaf(a0.y, w.y, fmaf(a0.z, w.z, fmaf(a0.w, w.w, acc0))));
            acc1 = fmaf(a1.x, w.x, fmaf(a1.y, w.y, fmaf(a1.z, w.z, fmaf(a1.w, w.w, acc1))));
            acc2 = fmaf(a2.x, w.x, fmaf(a2.y, w.y, fmaf(a2.z, w.z, fmaf(a2.w, w.w, acc2))));
            acc3 = fmaf(a3.x, w.x, fmaf(a3.y, w.y, fmaf(a3.z, w.z, fmaf(a3.w, w.w, acc3))));
        }

        float accs[4] = {acc0, acc1, acc2, acc3};
        #pragma unroll
        for (int r = 0; r < 4; ++r) {
            int row = rbase + xbase + r;
            if (row < N) {
                float d = rsqrtf((float)cnt[row] + 1.0f);
                g[(size_t)row * F_OUT + f] = f2bf(accs[r] * d);
            }
        }
    }
}

// ---- fused pull + epilogue: one block per coarse bucket (256 dsts) ----
// acc[ld][lane] in LDS; gather g[src] (bf16), ds_add_f32 accumulate;
// epilogue: agg = rsqrt(cnt+1)*(acc + g[d]); out = sigmoid(dot(relu(agg+b), W_lin)+bl)
__global__ __launch_bounds__(256) void k_fused(
    const unsigned short* __restrict__ g, const unsigned int* __restrict__ entries,
    const int* __restrict__ coarseOff, const int* __restrict__ cnt,
    const float* __restrict__ b_conv, const float* __restrict__ W_lin,
    const float* __restrict__ b_lin, float* __restrict__ out, int N) {
    __shared__ __align__(16) float acc[256 * F_OUT];   // 64 KB

    const int lane = threadIdx.x & 63;
    const int wave = threadIdx.x >> 6;

    // zero acc with float4 stores
    {
        float4* a4 = (float4*)acc;
        #pragma unroll
        for (int t = 0; t < 16; ++t)
            a4[t * 256 + threadIdx.x] = make_float4(0.f, 0.f, 0.f, 0.f);
    }
    __syncthreads();

    const int b     = blockIdx.x;
    const int start = coarseOff[b];
    const int end   = coarseOff[b + 1];

    for (int base = start + wave * 64; base < end; base += 256) {
        int n = min(64, end - base);
        unsigned int v = 0;
        if (lane < n) v = entries[base + lane];
        int j = 0;
        for (; j + 4 <= n; j += 4) {
            unsigned int v0 = __shfl(v, j + 0, 64);
            unsigned int v1 = __shfl(v, j + 1, 64);
            unsigned int v2 = __shfl(v, j + 2, 64);
            unsigned int v3 = __shfl(v, j + 3, 64);
            float f0 = bf2f(g[(size_t)(v0 & 0xFFFFFFu) * F_OUT + lane]);
            float f1 = bf2f(g[(size_t)(v1 & 0xFFFFFFu) * F_OUT + lane]);
            float f2 = bf2f(g[(size_t)(v2 & 0xFFFFFFu) * F_OUT + lane]);
            float f3 = bf2f(g[(size_t)(v3 & 0xFFFFFFu) * F_OUT + lane]);
            atomicAdd(&acc[(v0 >> 24) * F_OUT + lane], f0);
            atomicAdd(&acc[(v1 >> 24) * F_OUT + lane], f1);
            atomicAdd(&acc[(v2 >> 24) * F_OUT + lane], f2);
            atomicAdd(&acc[(v3 >> 24) * F_OUT + lane], f3);
        }
        for (; j < n; ++j) {
            unsigned int vj = __shfl(v, j, 64);
            float fj = bf2f(g[(size_t)(vj & 0xFFFFFFu) * F_OUT + lane]);
            atomicAdd(&acc[(vj >> 24) * F_OUT + lane], fj);
        }
    }
    __syncthreads();

    const float wl = W_lin[lane];
    const float bb = b_conv[lane];
    const float bl = b_lin[0];
    for (int ld = wave; ld < 256; ld += 4) {
        int d = (b << 8) + ld;
        if (d >= N) break;
        float row = acc[ld * F_OUT + lane] + bf2f(g[(size_t)d * F_OUT + lane]);
        float dinv = rsqrtf((float)cnt[d] + 1.0f);
        float a = fmaxf(row * dinv + bb, 0.f);
        float t = a * wl;
        #pragma unroll
        for (int off = 32; off > 0; off >>= 1)
            t += __shfl_down(t, off, 64);
        if (lane == 0)
            out[d] = 1.0f / (1.0f + expf(-(t + bl)));
    }
}

extern "C" void kernel_launch(void* const* d_in, const int* in_sizes, int n_in,
                              void* d_out, int out_size, void* d_ws, size_t ws_size,
                              hipStream_t stream) {
    const float* x      = (const float*)d_in[0];
    const int*   ei     = (const int*)d_in[1];
    const float* W_conv = (const float*)d_in[2];
    const float* b_conv = (const float*)d_in[3];
    const float* W_lin  = (const float*)d_in[4];
    const float* b_lin  = (const float*)d_in[5];

    const int N = in_sizes[0] / F_IN;     // 100000
    const int E = in_sizes[1] / 2;        // 1600000
    const int* src = ei;
    const int* dst = ei + E;
    float* out = (float*)d_out;

    const int NBC  = (N + 255) >> 8;            // coarse buckets (391)
    const int NBLK = (E + CHUNK - 1) / CHUNK;   // pass-A/B blocks (196)
    const int S    = NBC * NBLK;                // matrix elements (76,636)
    const int NB1  = (S + 255) / 256;           // scan blocks (300) <= 512

    const int Na = (N + 256) & ~255;
    const int Sa = (S + 256) & ~255;

    // workspace layout (4-byte units)
    int* cnt       = (int*)d_ws;                 // [Na]
    int* M         = cnt + Na;                   // [Sa]
    int* tmp       = M + Sa;                     // [Sa]
    int* bsum      = tmp + Sa;                   // [512]
    int* coarseOff = bsum + 512;                 // [NBC+1]
    unsigned int* entries = (unsigned int*)(coarseOff + ((NBC + 257) & ~255)); // [E]
    unsigned short* g = (unsigned short*)(entries + ((E + 255) & ~255));       // [N*64]

    hipMemsetAsync(cnt, 0, sizeof(int) * N, stream);
    k_hist   <<<NBLK, 256, 0, stream>>>(dst, E, cnt, M, NBLK, NBC);
    k_scan1  <<<NB1, 256, 0, stream>>>(M, tmp, bsum, S);
    k_scan2  <<<1, 512, 0, stream>>>(bsum, NB1);
    k_scan3  <<<NB1, 256, 0, stream>>>(M, tmp, bsum, coarseOff, S, NBLK, NBC, E);
    k_scatter<<<NBLK, 256, 0, stream>>>(src, dst, E, M, NBLK, NBC, entries);
    k_gemm   <<<(N + 63) / 64, 256, 0, stream>>>(x, W_conv, cnt, g, N);
    k_fused  <<<NBC, 256, 0, stream>>>(g, entries, coarseOff, cnt, b_conv, W_lin, b_lin, out, N);
}

// Round 4
// 233.993 us; speedup vs baseline: 4.1587x; 4.1587x over previous
//
#include <hip/hip_runtime.h>
#include <math.h>

#define F_IN   128
#define F_OUT  64
#define CHUNK  8192          // edges per hist/scatter block
#define MAXB   512           // max coarse buckets

__device__ __forceinline__ float bf2f(unsigned short u) {
    union { unsigned int i; float f; } c; c.i = ((unsigned int)u) << 16; return c.f;
}
__device__ __forceinline__ unsigned short f2bf(float f) {
    union { float f; unsigned int i; } c; c.f = f;
    unsigned int r = c.i + 0x7FFFu + ((c.i >> 16) & 1u);   // RNE
    return (unsigned short)(r >> 16);
}

// ---- pass A: per-block coarse histogram [bucket][block] (LDS only, no global atomics) ----
__global__ __launch_bounds__(256) void k_hist(
    const int* __restrict__ dst, int E, int* __restrict__ M, int NBLK, int NBC) {
    __shared__ int hist[MAXB];
    for (int c = threadIdx.x; c < MAXB; c += 256) hist[c] = 0;
    __syncthreads();
    int e0 = blockIdx.x * CHUNK;
    int e1 = min(E, e0 + CHUNK);
    for (int e = e0 + threadIdx.x; e < e1; e += 256)
        atomicAdd(&hist[dst[e] >> 8], 1);
    __syncthreads();
    for (int c = threadIdx.x; c < NBC; c += 256)
        M[c * NBLK + blockIdx.x] = hist[c];
}

// ---- flat exclusive scan over S = NBC*NBLK elements (3 phases) ----
__global__ void k_scan1(const int* __restrict__ M, int* __restrict__ tmp,
                        int* __restrict__ bsum, int S) {
    __shared__ int sh[256];
    int i = blockIdx.x * 256 + threadIdx.x;
    int v = (i < S) ? M[i] : 0;
    sh[threadIdx.x] = v;
    __syncthreads();
    for (int off = 1; off < 256; off <<= 1) {
        int t = (threadIdx.x >= off) ? sh[threadIdx.x - off] : 0;
        __syncthreads();
        sh[threadIdx.x] += t;
        __syncthreads();
    }
    if (i < S) tmp[i] = sh[threadIdx.x];
    if (threadIdx.x == 255) bsum[blockIdx.x] = sh[255];
}

__global__ void k_scan2(int* __restrict__ bsum, int NB1) {
    __shared__ int sh[512];
    int v = (threadIdx.x < NB1) ? bsum[threadIdx.x] : 0;
    sh[threadIdx.x] = v;
    __syncthreads();
    for (int off = 1; off < 512; off <<= 1) {
        int t = (threadIdx.x >= off) ? sh[threadIdx.x - off] : 0;
        __syncthreads();
        sh[threadIdx.x] += t;
        __syncthreads();
    }
    if (threadIdx.x < NB1) bsum[threadIdx.x] = sh[threadIdx.x] - v;   // exclusive
}

// scan3: M <- exclusive scan; extract bucketOff[bucket]; seed offsets[N]=E
__global__ void k_scan3(int* __restrict__ M, const int* __restrict__ tmp,
                        const int* __restrict__ bsum, int* __restrict__ bucketOff,
                        int* __restrict__ offsets,
                        int S, int NBLK, int NBC, int N, int E) {
    int i = blockIdx.x * 256 + threadIdx.x;
    if (i < S) {
        int orig = M[i];
        int o = tmp[i] - orig + bsum[blockIdx.x];
        M[i] = o;
        if (i % NBLK == 0) bucketOff[i / NBLK] = o;
    }
    if (i == 0) { bucketOff[NBC] = E; offsets[N] = E; }
}

// ---- pass B: scatter packed entries (localdst<<24 | src) into coarse buckets ----
__global__ __launch_bounds__(256) void k_scatter(
    const int* __restrict__ src, const int* __restrict__ dst, int E,
    const int* __restrict__ M, int NBLK, int NBC, unsigned int* __restrict__ entries) {
    __shared__ int cur[MAXB];
    for (int c = threadIdx.x; c < NBC; c += 256)
        cur[c] = M[c * NBLK + blockIdx.x];
    __syncthreads();
    int e0 = blockIdx.x * CHUNK;
    int e1 = min(E, e0 + CHUNK);
    for (int e = e0 + threadIdx.x; e < e1; e += 256) {
        int d = dst[e];
        int s = src[e];
        int p = atomicAdd(&cur[d >> 8], 1);
        entries[p] = ((unsigned int)(d & 255) << 24) | (unsigned int)s;
    }
}

// ---- per-bucket counting sort -> global CSR (offsets, srcs) ----
// one block per coarse bucket; all writes for a bucket go to its own
// contiguous 16KB window of srcs from a single block -> no cross-XCD ping-pong.
__global__ __launch_bounds__(256) void k_sort(
    const unsigned int* __restrict__ entries, const int* __restrict__ bucketOff,
    int* __restrict__ offsets, int* __restrict__ srcs, int N) {
    __shared__ int hist[256];
    __shared__ int curs[256];
    const int tid = threadIdx.x;
    const int b = blockIdx.x;
    const int start = bucketOff[b];
    const int end   = bucketOff[b + 1];

    hist[tid] = 0;
    __syncthreads();
    for (int i = start + tid; i < end; i += 256)
        atomicAdd(&hist[entries[i] >> 24], 1);
    __syncthreads();

    int cntv = hist[tid];
    curs[tid] = cntv;
    __syncthreads();
    for (int off = 1; off < 256; off <<= 1) {
        int t = (tid >= off) ? curs[tid - off] : 0;
        __syncthreads();
        curs[tid] += t;
        __syncthreads();
    }
    int excl = curs[tid] - cntv;          // exclusive scan within bucket
    int d = (b << 8) + tid;
    if (d < N) offsets[d] = start + excl;
    __syncthreads();
    curs[tid] = start + excl;             // cursors
    __syncthreads();

    for (int i = start + tid; i < end; i += 256) {
        unsigned int v = entries[i];
        int p = atomicAdd(&curs[v >> 24], 1);
        srcs[p] = (int)(v & 0xFFFFFFu);
    }
}

// ---- g = bf16( (x @ W^T) * rsqrt(indeg[row]+1) ) ----
__global__ __launch_bounds__(256) void k_gemm(
    const float* __restrict__ x, const float* __restrict__ W,
    const int* __restrict__ offsets, unsigned short* __restrict__ g, int N) {
    __shared__ float Ws[F_OUT * F_IN];   // swizzled, 32 KB
    __shared__ float xs[16 * F_IN];      // 8 KB

    const int tid = threadIdx.x;
    const int f   = tid & 63;
    const int rg  = tid >> 6;

    const float4* W4 = (const float4*)W;
    float4* Ws4 = (float4*)Ws;
    {
        int idx4 = tid;
        #pragma unroll
        for (int t = 0; t < 8; ++t, idx4 += 256) {
            int fr = idx4 >> 5;
            int q  = idx4 & 31;
            Ws4[fr * 32 + (q ^ (fr & 31))] = W4[idx4];
        }
    }

    const int row0 = blockIdx.x * 64;
    float4* xs4 = (float4*)xs;

    for (int c = 0; c < 4; ++c) {
        int rbase = row0 + c * 16;
        __syncthreads();
        {
            const float4* x4 = (const float4*)x;
            int idx4 = tid;
            #pragma unroll
            for (int t = 0; t < 2; ++t, idx4 += 256) {
                int r  = idx4 >> 5;
                int cq = idx4 & 31;
                int grow = rbase + r;
                float4 v = make_float4(0.f, 0.f, 0.f, 0.f);
                if (grow < N) v = x4[(size_t)grow * 32 + cq];
                xs4[r * 32 + cq] = v;
            }
        }
        __syncthreads();

        float acc0 = 0.f, acc1 = 0.f, acc2 = 0.f, acc3 = 0.f;
        const int xbase = rg * 4;
        #pragma unroll 4
        for (int q = 0; q < 32; ++q) {
            float4 w = Ws4[f * 32 + (q ^ (f & 31))];
            float4 a0 = xs4[(xbase + 0) * 32 + q];
            float4 a1 = xs4[(xbase + 1) * 32 + q];
            float4 a2 = xs4[(xbase + 2) * 32 + q];
            float4 a3 = xs4[(xbase + 3) * 32 + q];
            acc0 = fmaf(a0.x, w.x, fmaf(a0.y, w.y, fmaf(a0.z, w.z, fmaf(a0.w, w.w, acc0))));
            acc1 = fmaf(a1.x, w.x, fmaf(a1.y, w.y, fmaf(a1.z, w.z, fmaf(a1.w, w.w, acc1))));
            acc2 = fmaf(a2.x, w.x, fmaf(a2.y, w.y, fmaf(a2.z, w.z, fmaf(a2.w, w.w, acc2))));
            acc3 = fmaf(a3.x, w.x, fmaf(a3.y, w.y, fmaf(a3.z, w.z, fmaf(a3.w, w.w, acc3))));
        }

        float accs[4] = {acc0, acc1, acc2, acc3};
        #pragma unroll
        for (int r = 0; r < 4; ++r) {
            int row = rbase + xbase + r;
            if (row < N) {
                float deg = (float)(offsets[row + 1] - offsets[row]) + 1.0f;
                g[(size_t)row * F_OUT + f] = f2bf(accs[r] * rsqrtf(deg));
            }
        }
    }
}

// ---- pull aggregation + fused epilogue: wave per dst, lane = feature ----
__global__ __launch_bounds__(256) void k_pull(
    const unsigned short* __restrict__ g, const int* __restrict__ offsets,
    const int* __restrict__ srcs, const float* __restrict__ b_conv,
    const float* __restrict__ W_lin, const float* __restrict__ b_lin,
    float* __restrict__ out, int N) {
    const int lane   = threadIdx.x & 63;
    const int wave   = (blockIdx.x * blockDim.x + threadIdx.x) >> 6;
    const int nwaves = (gridDim.x * blockDim.x) >> 6;
    const float wl = W_lin[lane];
    const float bb = b_conv[lane];
    const float bl = b_lin[0];

    for (int i = wave; i < N; i += nwaves) {
        int e0 = __builtin_amdgcn_readfirstlane(offsets[i]);
        int e1 = __builtin_amdgcn_readfirstlane(offsets[i + 1]);
        float acc = bf2f(g[(size_t)i * F_OUT + lane]);   // self loop
        int e = e0;
        for (; e + 8 <= e1; e += 8) {
            int s0 = srcs[e + 0], s1 = srcs[e + 1], s2 = srcs[e + 2], s3 = srcs[e + 3];
            int s4 = srcs[e + 4], s5 = srcs[e + 5], s6 = srcs[e + 6], s7 = srcs[e + 7];
            float v0 = bf2f(g[(size_t)s0 * F_OUT + lane]);
            float v1 = bf2f(g[(size_t)s1 * F_OUT + lane]);
            float v2 = bf2f(g[(size_t)s2 * F_OUT + lane]);
            float v3 = bf2f(g[(size_t)s3 * F_OUT + lane]);
            float v4 = bf2f(g[(size_t)s4 * F_OUT + lane]);
            float v5 = bf2f(g[(size_t)s5 * F_OUT + lane]);
            float v6 = bf2f(g[(size_t)s6 * F_OUT + lane]);
            float v7 = bf2f(g[(size_t)s7 * F_OUT + lane]);
            acc += ((v0 + v1) + (v2 + v3)) + ((v4 + v5) + (v6 + v7));
        }
        for (; e < e1; ++e)
            acc += bf2f(g[(size_t)srcs[e] * F_OUT + lane]);

        float dinv = rsqrtf((float)(e1 - e0) + 1.0f);
        float a = fmaxf(acc * dinv + bb, 0.f);
        float t = a * wl;
        #pragma unroll
        for (int off = 32; off > 0; off >>= 1)
            t += __shfl_down(t, off, 64);
        if (lane == 0)
            out[i] = 1.0f / (1.0f + expf(-(t + bl)));
    }
}

extern "C" void kernel_launch(void* const* d_in, const int* in_sizes, int n_in,
                              void* d_out, int out_size, void* d_ws, size_t ws_size,
                              hipStream_t stream) {
    const float* x      = (const float*)d_in[0];
    const int*   ei     = (const int*)d_in[1];
    const float* W_conv = (const float*)d_in[2];
    const float* b_conv = (const float*)d_in[3];
    const float* W_lin  = (const float*)d_in[4];
    const float* b_lin  = (const float*)d_in[5];

    const int N = in_sizes[0] / F_IN;     // 100000
    const int E = in_sizes[1] / 2;        // 1600000
    const int* src = ei;
    const int* dst = ei + E;
    float* out = (float*)d_out;

    const int NBC  = (N + 255) >> 8;            // coarse buckets (391)
    const int NBLK = (E + CHUNK - 1) / CHUNK;   // hist/scatter blocks (196)
    const int S    = NBC * NBLK;                // 76,636
    const int NB1  = (S + 255) / 256;           // scan blocks (300) <= 512

    const int Na = (N + 256) & ~255;            // holds N+1
    const int Sa = (S + 256) & ~255;
    const int Ea = (E + 255) & ~255;

    // workspace layout (4-byte units)
    int* M         = (int*)d_ws;                 // [Sa]
    int* tmp       = M + Sa;                     // [Sa]
    int* bsum      = tmp + Sa;                   // [512]
    int* bucketOff = bsum + 512;                 // [NBC+1]
    int* offsets   = bucketOff + ((NBC + 257) & ~255); // [Na]
    unsigned int* entries = (unsigned int*)(offsets + Na);   // [E]
    int* srcs      = (int*)(entries + Ea);       // [E]
    unsigned short* g = (unsigned short*)(srcs + Ea);        // [N*64] bf16

    k_hist   <<<NBLK, 256, 0, stream>>>(dst, E, M, NBLK, NBC);
    k_scan1  <<<NB1, 256, 0, stream>>>(M, tmp, bsum, S);
    k_scan2  <<<1, 512, 0, stream>>>(bsum, NB1);
    k_scan3  <<<NB1, 256, 0, stream>>>(M, tmp, bsum, bucketOff, offsets, S, NBLK, NBC, N, E);
    k_scatter<<<NBLK, 256, 0, stream>>>(src, dst, E, M, NBLK, NBC, entries);
    k_sort   <<<NBC, 256, 0, stream>>>(entries, bucketOff, offsets, srcs, N);
    k_gemm   <<<(N + 63) / 64, 256, 0, stream>>>(x, W_conv, offsets, g, N);
    k_pull   <<<4096, 256, 0, stream>>>(g, offsets, srcs, b_conv, W_lin, b_lin, out, N);
}

// Round 5
// 202.506 us; speedup vs baseline: 4.8053x; 1.1555x over previous
//
#include <hip/hip_runtime.h>
#include <math.h>

#define F_IN   128
#define F_OUT  64
#define CHUNK  8192          // edges per hist/scatter block
#define MAXB   512           // max coarse buckets

typedef short bf16x8 __attribute__((ext_vector_type(8)));
typedef float f32x4  __attribute__((ext_vector_type(4)));

__device__ __forceinline__ float bf2f(unsigned short u) {
    union { unsigned int i; float f; } c; c.i = ((unsigned int)u) << 16; return c.f;
}
__device__ __forceinline__ unsigned short f2bf(float f) {
    union { float f; unsigned int i; } c; c.f = f;
    unsigned int r = c.i + 0x7FFFu + ((c.i >> 16) & 1u);   // RNE
    return (unsigned short)(r >> 16);
}

// ---- pass A: per-block coarse histogram [bucket][block] (LDS only) ----
__global__ __launch_bounds__(256) void k_hist(
    const int* __restrict__ dst, int E, int* __restrict__ M, int NBLK, int NBC) {
    __shared__ int hist[MAXB];
    for (int c = threadIdx.x; c < MAXB; c += 256) hist[c] = 0;
    __syncthreads();
    int e0 = blockIdx.x * CHUNK;
    int e1 = min(E, e0 + CHUNK);
    for (int e = e0 + threadIdx.x; e < e1; e += 256)
        atomicAdd(&hist[dst[e] >> 8], 1);
    __syncthreads();
    for (int c = threadIdx.x; c < NBC; c += 256)
        M[c * NBLK + blockIdx.x] = hist[c];
}

// ---- flat exclusive scan over S = NBC*NBLK elements (3 phases) ----
__global__ void k_scan1(const int* __restrict__ M, int* __restrict__ tmp,
                        int* __restrict__ bsum, int S) {
    __shared__ int sh[256];
    int i = blockIdx.x * 256 + threadIdx.x;
    int v = (i < S) ? M[i] : 0;
    sh[threadIdx.x] = v;
    __syncthreads();
    for (int off = 1; off < 256; off <<= 1) {
        int t = (threadIdx.x >= off) ? sh[threadIdx.x - off] : 0;
        __syncthreads();
        sh[threadIdx.x] += t;
        __syncthreads();
    }
    if (i < S) tmp[i] = sh[threadIdx.x];
    if (threadIdx.x == 255) bsum[blockIdx.x] = sh[255];
}

__global__ void k_scan2(int* __restrict__ bsum, int NB1) {
    __shared__ int sh[512];
    int v = (threadIdx.x < NB1) ? bsum[threadIdx.x] : 0;
    sh[threadIdx.x] = v;
    __syncthreads();
    for (int off = 1; off < 512; off <<= 1) {
        int t = (threadIdx.x >= off) ? sh[threadIdx.x - off] : 0;
        __syncthreads();
        sh[threadIdx.x] += t;
        __syncthreads();
    }
    if (threadIdx.x < NB1) bsum[threadIdx.x] = sh[threadIdx.x] - v;   // exclusive
}

// scan3: M <- exclusive scan; extract bucketOff[bucket]; seed offsets[N]=E
__global__ void k_scan3(int* __restrict__ M, const int* __restrict__ tmp,
                        const int* __restrict__ bsum, int* __restrict__ bucketOff,
                        int* __restrict__ offsets,
                        int S, int NBLK, int NBC, int N, int E) {
    int i = blockIdx.x * 256 + threadIdx.x;
    if (i < S) {
        int orig = M[i];
        int o = tmp[i] - orig + bsum[blockIdx.x];
        M[i] = o;
        if (i % NBLK == 0) bucketOff[i / NBLK] = o;
    }
    if (i == 0) { bucketOff[NBC] = E; offsets[N] = E; }
}

// ---- pass B: scatter packed entries (localdst<<24 | src) into coarse buckets ----
__global__ __launch_bounds__(256) void k_scatter(
    const int* __restrict__ src, const int* __restrict__ dst, int E,
    const int* __restrict__ M, int NBLK, int NBC, unsigned int* __restrict__ entries) {
    __shared__ int cur[MAXB];
    for (int c = threadIdx.x; c < NBC; c += 256)
        cur[c] = M[c * NBLK + blockIdx.x];
    __syncthreads();
    int e0 = blockIdx.x * CHUNK;
    int e1 = min(E, e0 + CHUNK);
    for (int e = e0 + threadIdx.x; e < e1; e += 256) {
        int d = dst[e];
        int s = src[e];
        int p = atomicAdd(&cur[d >> 8], 1);
        entries[p] = ((unsigned int)(d & 255) << 24) | (unsigned int)s;
    }
}

// ---- per-bucket counting sort -> global CSR (offsets, srcs) ----
__global__ __launch_bounds__(256) void k_sort(
    const unsigned int* __restrict__ entries, const int* __restrict__ bucketOff,
    int* __restrict__ offsets, int* __restrict__ srcs, int N) {
    __shared__ int hist[256];
    __shared__ int curs[256];
    const int tid = threadIdx.x;
    const int b = blockIdx.x;
    const int start = bucketOff[b];
    const int end   = bucketOff[b + 1];

    hist[tid] = 0;
    __syncthreads();
    for (int i = start + tid; i < end; i += 256)
        atomicAdd(&hist[entries[i] >> 24], 1);
    __syncthreads();

    int cntv = hist[tid];
    curs[tid] = cntv;
    __syncthreads();
    for (int off = 1; off < 256; off <<= 1) {
        int t = (tid >= off) ? curs[tid - off] : 0;
        __syncthreads();
        curs[tid] += t;
        __syncthreads();
    }
    int excl = curs[tid] - cntv;
    int d = (b << 8) + tid;
    if (d < N) offsets[d] = start + excl;
    __syncthreads();
    curs[tid] = start + excl;
    __syncthreads();

    for (int i = start + tid; i < end; i += 256) {
        unsigned int v = entries[i];
        int p = atomicAdd(&curs[v >> 24], 1);
        srcs[p] = (int)(v & 0xFFFFFFu);
    }
}

// ---- MFMA GEMM: g = bf16( (x @ W^T) * rsqrt(indeg[row]+1) ) ----
// block = 256 thr (4 waves), 64 rows/block, W+x tile staged as bf16 in LDS.
// wave w computes rows [w*16, w*16+16) x all 64 cols via 16 mfma_16x16x32_bf16.
// A[m][k]: m=lane&15, k=(lane>>4)*8+j  (verified m120)
// B[k][n]: n=lane&15, k=(lane>>4)*8+j  (verified m91-93 end-to-end)
// D[m][n]: n=lane&15, m=(lane>>4)*4+reg (verified m89)
__global__ __launch_bounds__(256) void k_gemm(
    const float* __restrict__ x, const float* __restrict__ W,
    const int* __restrict__ offsets, unsigned short* __restrict__ g, int N) {
    __shared__ unsigned short xs[64 * F_IN];   // 16 KB
    __shared__ unsigned short Wsh[F_OUT * F_IN]; // 16 KB
    __shared__ float dinvs[64];

    const int tid  = threadIdx.x;
    const int row0 = blockIdx.x * 64;

    // stage W: 8192 floats = 2048 float4, 8 per thread
    {
        const float4* W4 = (const float4*)W;
        #pragma unroll
        for (int t = 0; t < 8; ++t) {
            int idx = t * 256 + tid;
            float4 v = W4[idx];
            ushort4 u;
            u.x = f2bf(v.x); u.y = f2bf(v.y); u.z = f2bf(v.z); u.w = f2bf(v.w);
            *(ushort4*)&Wsh[idx * 4] = u;
        }
    }
    // stage x tile: 64 rows x 128 = 2048 float4, 8 per thread (guarded)
    {
        const float4* x4 = (const float4*)x;
        #pragma unroll
        for (int t = 0; t < 8; ++t) {
            int idx = t * 256 + tid;
            int r = idx >> 5;            // row within tile
            int grow = row0 + r;
            float4 v = make_float4(0.f, 0.f, 0.f, 0.f);
            if (grow < N) v = x4[(size_t)grow * 32 + (idx & 31)];
            ushort4 u;
            u.x = f2bf(v.x); u.y = f2bf(v.y); u.z = f2bf(v.z); u.w = f2bf(v.w);
            *(ushort4*)&xs[idx * 4] = u;
        }
    }
    // dinv per row
    if (tid < 64) {
        int grow = row0 + tid;
        float dv = 1.0f;
        if (grow < N) dv = rsqrtf((float)(offsets[grow + 1] - offsets[grow]) + 1.0f);
        dinvs[tid] = dv;
    }
    __syncthreads();

    const int lane = tid & 63;
    const int wave = tid >> 6;
    const int m = lane & 15;
    const int q = lane >> 4;           // 0..3
    const int r0 = wave * 16;          // wave's row tile within block

    // A fragments: 4 k-steps
    bf16x8 a[4];
    #pragma unroll
    for (int ks = 0; ks < 4; ++ks)
        a[ks] = *(const bf16x8*)&xs[(r0 + m) * F_IN + ks * 32 + q * 8];

    f32x4 acc[4] = {{0,0,0,0},{0,0,0,0},{0,0,0,0},{0,0,0,0}};
    #pragma unroll
    for (int ct = 0; ct < 4; ++ct) {
        #pragma unroll
        for (int ks = 0; ks < 4; ++ks) {
            bf16x8 b = *(const bf16x8*)&Wsh[(ct * 16 + m) * F_IN + ks * 32 + q * 8];
            acc[ct] = __builtin_amdgcn_mfma_f32_16x16x32_bf16(a[ks], b, acc[ct], 0, 0, 0);
        }
    }

    // epilogue: scale by dinv, cast bf16, store
    float dv[4];
    #pragma unroll
    for (int reg = 0; reg < 4; ++reg)
        dv[reg] = dinvs[r0 + q * 4 + reg];
    #pragma unroll
    for (int ct = 0; ct < 4; ++ct) {
        #pragma unroll
        for (int reg = 0; reg < 4; ++reg) {
            int grow = row0 + r0 + q * 4 + reg;
            if (grow < N)
                g[(size_t)grow * F_OUT + ct * 16 + m] = f2bf(acc[ct][reg] * dv[reg]);
        }
    }
}

// ---- pull aggregation + fused epilogue: wave per dst, lane = feature ----
__global__ __launch_bounds__(256) void k_pull(
    const unsigned short* __restrict__ g, const int* __restrict__ offsets,
    const int* __restrict__ srcs, const float* __restrict__ b_conv,
    const float* __restrict__ W_lin, const float* __restrict__ b_lin,
    float* __restrict__ out, int N) {
    const int lane   = threadIdx.x & 63;
    const int wave   = (blockIdx.x * blockDim.x + threadIdx.x) >> 6;
    const int nwaves = (gridDim.x * blockDim.x) >> 6;
    const float wl = W_lin[lane];
    const float bb = b_conv[lane];
    const float bl = b_lin[0];

    for (int i = wave; i < N; i += nwaves) {
        int e0 = __builtin_amdgcn_readfirstlane(offsets[i]);
        int e1 = __builtin_amdgcn_readfirstlane(offsets[i + 1]);
        float acc = bf2f(g[(size_t)i * F_OUT + lane]);   // self loop
        int e = e0;
        for (; e + 8 <= e1; e += 8) {
            int s0 = srcs[e + 0], s1 = srcs[e + 1], s2 = srcs[e + 2], s3 = srcs[e + 3];
            int s4 = srcs[e + 4], s5 = srcs[e + 5], s6 = srcs[e + 6], s7 = srcs[e + 7];
            float v0 = bf2f(g[(size_t)s0 * F_OUT + lane]);
            float v1 = bf2f(g[(size_t)s1 * F_OUT + lane]);
            float v2 = bf2f(g[(size_t)s2 * F_OUT + lane]);
            float v3 = bf2f(g[(size_t)s3 * F_OUT + lane]);
            float v4 = bf2f(g[(size_t)s4 * F_OUT + lane]);
            float v5 = bf2f(g[(size_t)s5 * F_OUT + lane]);
            float v6 = bf2f(g[(size_t)s6 * F_OUT + lane]);
            float v7 = bf2f(g[(size_t)s7 * F_OUT + lane]);
            acc += ((v0 + v1) + (v2 + v3)) + ((v4 + v5) + (v6 + v7));
        }
        for (; e < e1; ++e)
            acc += bf2f(g[(size_t)srcs[e] * F_OUT + lane]);

        float dinv = rsqrtf((float)(e1 - e0) + 1.0f);
        float a = fmaxf(acc * dinv + bb, 0.f);
        float t = a * wl;
        #pragma unroll
        for (int off = 32; off > 0; off >>= 1)
            t += __shfl_down(t, off, 64);
        if (lane == 0)
            out[i] = 1.0f / (1.0f + expf(-(t + bl)));
    }
}

extern "C" void kernel_launch(void* const* d_in, const int* in_sizes, int n_in,
                              void* d_out, int out_size, void* d_ws, size_t ws_size,
                              hipStream_t stream) {
    const float* x      = (const float*)d_in[0];
    const int*   ei     = (const int*)d_in[1];
    const float* W_conv = (const float*)d_in[2];
    const float* b_conv = (const float*)d_in[3];
    const float* W_lin  = (const float*)d_in[4];
    const float* b_lin  = (const float*)d_in[5];

    const int N = in_sizes[0] / F_IN;     // 100000
    const int E = in_sizes[1] / 2;        // 1600000
    const int* src = ei;
    const int* dst = ei + E;
    float* out = (float*)d_out;

    const int NBC  = (N + 255) >> 8;            // coarse buckets (391)
    const int NBLK = (E + CHUNK - 1) / CHUNK;   // hist/scatter blocks (196)
    const int S    = NBC * NBLK;                // 76,636
    const int NB1  = (S + 255) / 256;           // scan blocks (300) <= 512

    const int Na = (N + 256) & ~255;            // holds N+1
    const int Sa = (S + 256) & ~255;
    const int Ea = (E + 255) & ~255;

    // workspace layout (4-byte units)
    int* M         = (int*)d_ws;                 // [Sa]
    int* tmp       = M + Sa;                     // [Sa]
    int* bsum      = tmp + Sa;                   // [512]
    int* bucketOff = bsum + 512;                 // [NBC+1]
    int* offsets   = bucketOff + ((NBC + 257) & ~255); // [Na]
    unsigned int* entries = (unsigned int*)(offsets + Na);   // [E]
    int* srcs      = (int*)(entries + Ea);       // [E]
    unsigned short* g = (unsigned short*)(srcs + Ea);        // [N*64] bf16

    k_hist   <<<NBLK, 256, 0, stream>>>(dst, E, M, NBLK, NBC);
    k_scan1  <<<NB1, 256, 0, stream>>>(M, tmp, bsum, S);
    k_scan2  <<<1, 512, 0, stream>>>(bsum, NB1);
    k_scan3  <<<NB1, 256, 0, stream>>>(M, tmp, bsum, bucketOff, offsets, S, NBLK, NBC, N, E);
    k_scatter<<<NBLK, 256, 0, stream>>>(src, dst, E, M, NBLK, NBC, entries);
    k_sort   <<<NBC, 256, 0, stream>>>(entries, bucketOff, offsets, srcs, N);
    k_gemm   <<<(N + 63) / 64, 256, 0, stream>>>(x, W_conv, offsets, g, N);
    k_pull   <<<4096, 256, 0, stream>>>(g, offsets, srcs, b_conv, W_lin, b_lin, out, N);
}

// Round 6
// 198.234 us; speedup vs baseline: 4.9089x; 1.0216x over previous
//
#include <hip/hip_runtime.h>
#include <math.h>

#define F_IN   128
#define F_OUT  64
#define CHUNK  5120          // edges per hist/scatter block
#define MAXB   512           // max coarse buckets

typedef short bf16x8 __attribute__((ext_vector_type(8)));
typedef float f32x4  __attribute__((ext_vector_type(4)));

__device__ __forceinline__ float bf2f(unsigned short u) {
    union { unsigned int i; float f; } c; c.i = ((unsigned int)u) << 16; return c.f;
}
__device__ __forceinline__ unsigned short f2bf(float f) {
    union { float f; unsigned int i; } c; c.f = f;
    unsigned int r = c.i + 0x7FFFu + ((c.i >> 16) & 1u);   // RNE
    return (unsigned short)(r >> 16);
}

// ---- pass A: per-block coarse histogram [bucket][block] (LDS only) ----
__global__ __launch_bounds__(256) void k_hist(
    const int* __restrict__ dst, int E, int* __restrict__ M, int NBLK, int NBC) {
    __shared__ int hist[MAXB];
    for (int c = threadIdx.x; c < MAXB; c += 256) hist[c] = 0;
    __syncthreads();
    int e0 = blockIdx.x * CHUNK;
    int e1 = min(E, e0 + CHUNK);
    for (int e = e0 + threadIdx.x; e < e1; e += 256)
        atomicAdd(&hist[dst[e] >> 8], 1);
    __syncthreads();
    for (int c = threadIdx.x; c < NBC; c += 256)
        M[c * NBLK + blockIdx.x] = hist[c];
}

// ---- flat exclusive scan over S = NBC*NBLK elements (3 phases) ----
__global__ void k_scan1(const int* __restrict__ M, int* __restrict__ tmp,
                        int* __restrict__ bsum, int S) {
    __shared__ int sh[256];
    int i = blockIdx.x * 256 + threadIdx.x;
    int v = (i < S) ? M[i] : 0;
    sh[threadIdx.x] = v;
    __syncthreads();
    for (int off = 1; off < 256; off <<= 1) {
        int t = (threadIdx.x >= off) ? sh[threadIdx.x - off] : 0;
        __syncthreads();
        sh[threadIdx.x] += t;
        __syncthreads();
    }
    if (i < S) tmp[i] = sh[threadIdx.x];
    if (threadIdx.x == 255) bsum[blockIdx.x] = sh[255];
}

__global__ void k_scan2(int* __restrict__ bsum, int NB1) {
    __shared__ int sh[512];
    int v = (threadIdx.x < NB1) ? bsum[threadIdx.x] : 0;
    sh[threadIdx.x] = v;
    __syncthreads();
    for (int off = 1; off < 512; off <<= 1) {
        int t = (threadIdx.x >= off) ? sh[threadIdx.x - off] : 0;
        __syncthreads();
        sh[threadIdx.x] += t;
        __syncthreads();
    }
    if (threadIdx.x < NB1) bsum[threadIdx.x] = sh[threadIdx.x] - v;   // exclusive
}

// scan3: M <- exclusive scan; extract bucketOff[bucket]; seed offsets[N]=E
__global__ void k_scan3(int* __restrict__ M, const int* __restrict__ tmp,
                        const int* __restrict__ bsum, int* __restrict__ bucketOff,
                        int* __restrict__ offsets,
                        int S, int NBLK, int NBC, int N, int E) {
    int i = blockIdx.x * 256 + threadIdx.x;
    if (i < S) {
        int orig = M[i];
        int o = tmp[i] - orig + bsum[blockIdx.x];
        M[i] = o;
        if (i % NBLK == 0) bucketOff[i / NBLK] = o;
    }
    if (i == 0) { bucketOff[NBC] = E; offsets[N] = E; }
}

// ---- pass B: scatter packed entries (localdst<<24 | src) into coarse buckets ----
__global__ __launch_bounds__(256) void k_scatter(
    const int* __restrict__ src, const int* __restrict__ dst, int E,
    const int* __restrict__ M, int NBLK, int NBC, unsigned int* __restrict__ entries) {
    __shared__ int cur[MAXB];
    for (int c = threadIdx.x; c < NBC; c += 256)
        cur[c] = M[c * NBLK + blockIdx.x];
    __syncthreads();
    int e0 = blockIdx.x * CHUNK;
    int e1 = min(E, e0 + CHUNK);
    for (int e = e0 + threadIdx.x; e < e1; e += 256) {
        int d = dst[e];
        int s = src[e];
        int p = atomicAdd(&cur[d >> 8], 1);
        entries[p] = ((unsigned int)(d & 255) << 24) | (unsigned int)s;
    }
}

// ---- per-bucket counting sort -> global CSR (offsets, srcs) ----
__global__ __launch_bounds__(256) void k_sort(
    const unsigned int* __restrict__ entries, const int* __restrict__ bucketOff,
    int* __restrict__ offsets, int* __restrict__ srcs, int N) {
    __shared__ int hist[256];
    __shared__ int curs[256];
    const int tid = threadIdx.x;
    const int b = blockIdx.x;
    const int start = bucketOff[b];
    const int end   = bucketOff[b + 1];

    hist[tid] = 0;
    __syncthreads();
    for (int i = start + tid; i < end; i += 256)
        atomicAdd(&hist[entries[i] >> 24], 1);
    __syncthreads();

    int cntv = hist[tid];
    curs[tid] = cntv;
    __syncthreads();
    for (int off = 1; off < 256; off <<= 1) {
        int t = (tid >= off) ? curs[tid - off] : 0;
        __syncthreads();
        curs[tid] += t;
        __syncthreads();
    }
    int excl = curs[tid] - cntv;
    int d = (b << 8) + tid;
    if (d < N) offsets[d] = start + excl;
    __syncthreads();
    curs[tid] = start + excl;
    __syncthreads();

    for (int i = start + tid; i < end; i += 256) {
        unsigned int v = entries[i];
        int p = atomicAdd(&curs[v >> 24], 1);
        srcs[p] = (int)(v & 0xFFFFFFu);
    }
}

// ---- MFMA GEMM: g = bf16( (x @ W^T) * rsqrt(indeg[row]+1) ) ----
__global__ __launch_bounds__(256) void k_gemm(
    const float* __restrict__ x, const float* __restrict__ W,
    const int* __restrict__ offsets, unsigned short* __restrict__ g, int N) {
    __shared__ unsigned short xs[64 * F_IN];     // 16 KB
    __shared__ unsigned short Wsh[F_OUT * F_IN]; // 16 KB
    __shared__ float dinvs[64];

    const int tid  = threadIdx.x;
    const int row0 = blockIdx.x * 64;

    {
        const float4* W4 = (const float4*)W;
        #pragma unroll
        for (int t = 0; t < 8; ++t) {
            int idx = t * 256 + tid;
            float4 v = W4[idx];
            ushort4 u;
            u.x = f2bf(v.x); u.y = f2bf(v.y); u.z = f2bf(v.z); u.w = f2bf(v.w);
            *(ushort4*)&Wsh[idx * 4] = u;
        }
    }
    {
        const float4* x4 = (const float4*)x;
        #pragma unroll
        for (int t = 0; t < 8; ++t) {
            int idx = t * 256 + tid;
            int r = idx >> 5;
            int grow = row0 + r;
            float4 v = make_float4(0.f, 0.f, 0.f, 0.f);
            if (grow < N) v = x4[(size_t)grow * 32 + (idx & 31)];
            ushort4 u;
            u.x = f2bf(v.x); u.y = f2bf(v.y); u.z = f2bf(v.z); u.w = f2bf(v.w);
            *(ushort4*)&xs[idx * 4] = u;
        }
    }
    if (tid < 64) {
        int grow = row0 + tid;
        float dv = 1.0f;
        if (grow < N) dv = rsqrtf((float)(offsets[grow + 1] - offsets[grow]) + 1.0f);
        dinvs[tid] = dv;
    }
    __syncthreads();

    const int lane = tid & 63;
    const int wave = tid >> 6;
    const int m = lane & 15;
    const int q = lane >> 4;
    const int r0 = wave * 16;

    bf16x8 a[4];
    #pragma unroll
    for (int ks = 0; ks < 4; ++ks)
        a[ks] = *(const bf16x8*)&xs[(r0 + m) * F_IN + ks * 32 + q * 8];

    f32x4 acc[4] = {{0,0,0,0},{0,0,0,0},{0,0,0,0},{0,0,0,0}};
    #pragma unroll
    for (int ct = 0; ct < 4; ++ct) {
        #pragma unroll
        for (int ks = 0; ks < 4; ++ks) {
            bf16x8 b = *(const bf16x8*)&Wsh[(ct * 16 + m) * F_IN + ks * 32 + q * 8];
            acc[ct] = __builtin_amdgcn_mfma_f32_16x16x32_bf16(a[ks], b, acc[ct], 0, 0, 0);
        }
    }

    float dv[4];
    #pragma unroll
    for (int reg = 0; reg < 4; ++reg)
        dv[reg] = dinvs[r0 + q * 4 + reg];
    #pragma unroll
    for (int ct = 0; ct < 4; ++ct) {
        #pragma unroll
        for (int reg = 0; reg < 4; ++reg) {
            int grow = row0 + r0 + q * 4 + reg;
            if (grow < N)
                g[(size_t)grow * F_OUT + ct * 16 + m] = f2bf(acc[ct][reg] * dv[reg]);
        }
    }
}

// ---- pull aggregation + fused epilogue: wave per dst, 2 edges/iteration ----
// half = lane>>5 selects edge within a pair; lane&31 covers 2 features (packed uint).
// After edge loop, halves are combined with shfl_xor(32); the 64-lane dot then
// counts every feature twice -> 0.5x in the logit.
__global__ __launch_bounds__(256) void k_pull(
    const unsigned short* __restrict__ g, const int* __restrict__ offsets,
    const int* __restrict__ srcs, const float* __restrict__ b_conv,
    const float* __restrict__ W_lin, const float* __restrict__ b_lin,
    float* __restrict__ out, int N) {
    const int lane   = threadIdx.x & 63;
    const int li     = lane & 31;
    const int half   = lane >> 5;
    const int wave   = (blockIdx.x * blockDim.x + threadIdx.x) >> 6;
    const int nwaves = (gridDim.x * blockDim.x) >> 6;

    const float2 wl = ((const float2*)W_lin)[li];
    const float2 bb = ((const float2*)b_conv)[li];
    const float  bl = b_lin[0];
    const unsigned int* g32 = (const unsigned int*)g;   // row = 32 uints (2 bf16 each)

    for (int i = wave; i < N; i += nwaves) {
        int e0 = __builtin_amdgcn_readfirstlane(offsets[i]);
        int e1 = __builtin_amdgcn_readfirstlane(offsets[i + 1]);

        // self loop: lower half only (upper half reads same line, adds 0)
        unsigned int us = g32[(size_t)i * 32 + li];
        float a0 = half ? 0.f : bf2f((unsigned short)(us & 0xFFFFu));
        float a1 = half ? 0.f : bf2f((unsigned short)(us >> 16));

        int e = e0;
        int M16 = e0 + ((e1 - e0) & ~15);
        for (; e < M16; e += 16) {
            unsigned int u[8];
            #pragma unroll
            for (int t = 0; t < 8; ++t) {
                int sA = srcs[e + 2 * t];
                int sB = srcs[e + 2 * t + 1];
                int s  = half ? sB : sA;
                u[t] = g32[(size_t)s * 32 + li];
            }
            #pragma unroll
            for (int t = 0; t < 8; ++t) {
                a0 += bf2f((unsigned short)(u[t] & 0xFFFFu));
                a1 += bf2f((unsigned short)(u[t] >> 16));
            }
        }
        for (; e + 2 <= e1; e += 2) {
            int sA = srcs[e];
            int sB = srcs[e + 1];
            int s  = half ? sB : sA;
            unsigned int u = g32[(size_t)s * 32 + li];
            a0 += bf2f((unsigned short)(u & 0xFFFFu));
            a1 += bf2f((unsigned short)(u >> 16));
        }
        if (e < e1 && half == 0) {           // odd tail edge: lower half only
            int s = srcs[e];
            unsigned int u = g32[(size_t)s * 32 + li];
            a0 += bf2f((unsigned short)(u & 0xFFFFu));
            a1 += bf2f((unsigned short)(u >> 16));
        }

        // combine the two half-wave partial sums (features need full sum before relu)
        a0 += __shfl_xor(a0, 32, 64);
        a1 += __shfl_xor(a1, 32, 64);

        float dinv = rsqrtf((float)(e1 - e0) + 1.0f);
        float r0 = fmaxf(a0 * dinv + bb.x, 0.f);
        float r1 = fmaxf(a1 * dinv + bb.y, 0.f);
        float t = r0 * wl.x + r1 * wl.y;
        #pragma unroll
        for (int off = 32; off > 0; off >>= 1)
            t += __shfl_down(t, off, 64);
        if (lane == 0)
            out[i] = 1.0f / (1.0f + expf(-(0.5f * t + bl)));   // 0.5: features duplicated across halves
    }
}

extern "C" void kernel_launch(void* const* d_in, const int* in_sizes, int n_in,
                              void* d_out, int out_size, void* d_ws, size_t ws_size,
                              hipStream_t stream) {
    const float* x      = (const float*)d_in[0];
    const int*   ei     = (const int*)d_in[1];
    const float* W_conv = (const float*)d_in[2];
    const float* b_conv = (const float*)d_in[3];
    const float* W_lin  = (const float*)d_in[4];
    const float* b_lin  = (const float*)d_in[5];

    const int N = in_sizes[0] / F_IN;     // 100000
    const int E = in_sizes[1] / 2;        // 1600000
    const int* src = ei;
    const int* dst = ei + E;
    float* out = (float*)d_out;

    const int NBC  = (N + 255) >> 8;            // coarse buckets (391)
    const int NBLK = (E + CHUNK - 1) / CHUNK;   // hist/scatter blocks (313)
    const int S    = NBC * NBLK;                // ~122k
    const int NB1  = (S + 255) / 256;           // scan blocks (479) <= 512

    const int Na = (N + 256) & ~255;            // holds N+1
    const int Sa = (S + 256) & ~255;
    const int Ea = (E + 255) & ~255;

    // workspace layout (4-byte units)
    int* M         = (int*)d_ws;                 // [Sa]
    int* tmp       = M + Sa;                     // [Sa]
    int* bsum      = tmp + Sa;                   // [512]
    int* bucketOff = bsum + 512;                 // [NBC+1]
    int* offsets   = bucketOff + ((NBC + 257) & ~255); // [Na]
    unsigned int* entries = (unsigned int*)(offsets + Na);   // [E]
    int* srcs      = (int*)(entries + Ea);       // [E]
    unsigned short* g = (unsigned short*)(srcs + Ea);        // [N*64] bf16

    k_hist   <<<NBLK, 256, 0, stream>>>(dst, E, M, NBLK, NBC);
    k_scan1  <<<NB1, 256, 0, stream>>>(M, tmp, bsum, S);
    k_scan2  <<<1, 512, 0, stream>>>(bsum, NB1);
    k_scan3  <<<NB1, 256, 0, stream>>>(M, tmp, bsum, bucketOff, offsets, S, NBLK, NBC, N, E);
    k_scatter<<<NBLK, 256, 0, stream>>>(src, dst, E, M, NBLK, NBC, entries);
    k_sort   <<<NBC, 256, 0, stream>>>(entries, bucketOff, offsets, srcs, N);
    k_gemm   <<<(N + 63) / 64, 256, 0, stream>>>(x, W_conv, offsets, g, N);
    k_pull   <<<4096, 256, 0, stream>>>(g, offsets, srcs, b_conv, W_lin, b_lin, out, N);
}

// Round 7
// 193.172 us; speedup vs baseline: 5.0375x; 1.0262x over previous
//
#include <hip/hip_runtime.h>
#include <hip/hip_bf16.h>
#include <math.h>

#define F_IN   128
#define F_OUT  64
#define CHUNK  5120          // edges per hist/scatter block
#define MAXB   512           // max coarse buckets
#define PADSLACK 4096        // per-bucket padded-window slack (256 dsts * 15 max pad)

typedef short bf16x8 __attribute__((ext_vector_type(8)));
typedef float f32x4  __attribute__((ext_vector_type(4)));

__device__ __forceinline__ float bf2f(unsigned short u) {
    union { unsigned int i; float f; } c; c.i = ((unsigned int)u) << 16; return c.f;
}
__device__ __forceinline__ unsigned short f2bf(float f) {
    union { float f; unsigned int i; } c; c.f = f;
    unsigned int r = c.i + 0x7FFFu + ((c.i >> 16) & 1u);   // RNE
    return (unsigned short)(r >> 16);
}
__device__ __forceinline__ unsigned int pk2bf(float a, float b) {
    __hip_bfloat162 p = __float22bfloat162_rn(make_float2(a, b));  // v_cvt_pk_bf16_f32
    union { __hip_bfloat162 h; unsigned int u; } c; c.h = p; return c.u;
}

// ---- pass A: per-block coarse histogram [bucket][block] (LDS only) ----
__global__ __launch_bounds__(256) void k_hist(
    const int* __restrict__ dst, int E, int* __restrict__ M, int NBLK, int NBC) {
    __shared__ int hist[MAXB];
    for (int c = threadIdx.x; c < MAXB; c += 256) hist[c] = 0;
    __syncthreads();
    int e0 = blockIdx.x * CHUNK;
    int e1 = min(E, e0 + CHUNK);
    for (int e = e0 + threadIdx.x; e < e1; e += 256)
        atomicAdd(&hist[dst[e] >> 8], 1);
    __syncthreads();
    for (int c = threadIdx.x; c < NBC; c += 256)
        M[c * NBLK + blockIdx.x] = hist[c];
}

// ---- flat exclusive scan over S = NBC*NBLK elements (3 phases) ----
__global__ void k_scan1(const int* __restrict__ M, int* __restrict__ tmp,
                        int* __restrict__ bsum, int S) {
    __shared__ int sh[256];
    int i = blockIdx.x * 256 + threadIdx.x;
    int v = (i < S) ? M[i] : 0;
    sh[threadIdx.x] = v;
    __syncthreads();
    for (int off = 1; off < 256; off <<= 1) {
        int t = (threadIdx.x >= off) ? sh[threadIdx.x - off] : 0;
        __syncthreads();
        sh[threadIdx.x] += t;
        __syncthreads();
    }
    if (i < S) tmp[i] = sh[threadIdx.x];
    if (threadIdx.x == 255) bsum[blockIdx.x] = sh[255];
}

__global__ void k_scan2(int* __restrict__ bsum, int NB1) {
    __shared__ int sh[512];
    int v = (threadIdx.x < NB1) ? bsum[threadIdx.x] : 0;
    sh[threadIdx.x] = v;
    __syncthreads();
    for (int off = 1; off < 512; off <<= 1) {
        int t = (threadIdx.x >= off) ? sh[threadIdx.x - off] : 0;
        __syncthreads();
        sh[threadIdx.x] += t;
        __syncthreads();
    }
    if (threadIdx.x < NB1) bsum[threadIdx.x] = sh[threadIdx.x] - v;   // exclusive
}

// scan3: M <- exclusive scan; extract bucketOff[bucket]
__global__ void k_scan3(int* __restrict__ M, const int* __restrict__ tmp,
                        const int* __restrict__ bsum, int* __restrict__ bucketOff,
                        int S, int NBLK, int NBC, int E) {
    int i = blockIdx.x * 256 + threadIdx.x;
    if (i < S) {
        int orig = M[i];
        int o = tmp[i] - orig + bsum[blockIdx.x];
        M[i] = o;
        if (i % NBLK == 0) bucketOff[i / NBLK] = o;
    }
    if (i == 0) bucketOff[NBC] = E;
}

// ---- pass B: scatter packed entries (localdst<<24 | src) into coarse buckets ----
__global__ __launch_bounds__(256) void k_scatter(
    const int* __restrict__ src, const int* __restrict__ dst, int E,
    const int* __restrict__ M, int NBLK, int NBC, unsigned int* __restrict__ entries) {
    __shared__ int cur[MAXB];
    for (int c = threadIdx.x; c < NBC; c += 256)
        cur[c] = M[c * NBLK + blockIdx.x];
    __syncthreads();
    int e0 = blockIdx.x * CHUNK;
    int e1 = min(E, e0 + CHUNK);
    for (int e = e0 + threadIdx.x; e < e1; e += 256) {
        int d = dst[e];
        int s = src[e];
        int p = atomicAdd(&cur[d >> 8], 1);
        entries[p] = ((unsigned int)(d & 255) << 24) | (unsigned int)s;
    }
}

// ---- per-bucket counting sort -> PADDED global CSR ----
// Lists padded to multiple of 16 with sentinel src = N (g[N] is a zero row).
// Padded window for bucket b starts at bucketOff[b] + b*PADSLACK.
__global__ __launch_bounds__(256) void k_sort(
    const unsigned int* __restrict__ entries, const int* __restrict__ bucketOff,
    int* __restrict__ offsetsP, int* __restrict__ deg,
    int* __restrict__ srcsP, int N) {
    __shared__ int hist[256];
    __shared__ int curs[256];
    const int tid = threadIdx.x;
    const int b = blockIdx.x;
    const int start = bucketOff[b];
    const int end   = bucketOff[b + 1];
    const int startP = start + b * PADSLACK;

    hist[tid] = 0;
    __syncthreads();
    for (int i = start + tid; i < end; i += 256)
        atomicAdd(&hist[entries[i] >> 24], 1);
    __syncthreads();

    int cntv   = hist[tid];
    int padded = (cntv + 15) & ~15;        // 0 stays 0
    curs[tid] = padded;
    __syncthreads();
    for (int off = 1; off < 256; off <<= 1) {
        int t = (tid >= off) ? curs[tid - off] : 0;
        __syncthreads();
        curs[tid] += t;
        __syncthreads();
    }
    int exclP = curs[tid] - padded;
    int d = (b << 8) + tid;
    if (d < N) { offsetsP[d] = startP + exclP; deg[d] = cntv; }
    __syncthreads();
    curs[tid] = startP + exclP;            // scatter cursors
    __syncthreads();

    for (int i = start + tid; i < end; i += 256) {
        unsigned int v = entries[i];
        int p = atomicAdd(&curs[v >> 24], 1);
        srcsP[p] = (int)(v & 0xFFFFFFu);
    }
    __syncthreads();

    // pad own dst's list with sentinel N
    int padEnd = startP + exclP + padded;
    for (int p = curs[tid]; p < padEnd; ++p)
        srcsP[p] = N;
}

// ---- MFMA GEMM: g = bf16( (x @ W^T) * rsqrt(deg[row]+1) ); g[N] = zero row ----
__global__ __launch_bounds__(256) void k_gemm(
    const float* __restrict__ x, const float* __restrict__ W,
    const int* __restrict__ deg, unsigned short* __restrict__ g, int N) {
    __shared__ unsigned short xs[64 * F_IN];     // 16 KB
    __shared__ unsigned short Wsh[F_OUT * F_IN]; // 16 KB
    __shared__ float dinvs[64];

    const int tid  = threadIdx.x;
    const int row0 = blockIdx.x * 64;

    {
        const float4* W4 = (const float4*)W;
        #pragma unroll
        for (int t = 0; t < 8; ++t) {
            int idx = t * 256 + tid;
            float4 v = W4[idx];
            uint2 u = make_uint2(pk2bf(v.x, v.y), pk2bf(v.z, v.w));
            *(uint2*)&Wsh[idx * 4] = u;
        }
    }
    {
        const float4* x4 = (const float4*)x;
        #pragma unroll
        for (int t = 0; t < 8; ++t) {
            int idx = t * 256 + tid;
            int r = idx >> 5;
            int grow = row0 + r;
            float4 v = make_float4(0.f, 0.f, 0.f, 0.f);
            if (grow < N) v = x4[(size_t)grow * 32 + (idx & 31)];
            uint2 u = make_uint2(pk2bf(v.x, v.y), pk2bf(v.z, v.w));
            *(uint2*)&xs[idx * 4] = u;
        }
    }
    if (tid < 64) {
        int grow = row0 + tid;
        float dv = 1.0f;
        if (grow < N) dv = rsqrtf((float)deg[grow] + 1.0f);
        dinvs[tid] = dv;
    }
    __syncthreads();

    const int lane = tid & 63;
    const int wave = tid >> 6;
    const int m = lane & 15;
    const int q = lane >> 4;
    const int r0 = wave * 16;

    bf16x8 a[4];
    #pragma unroll
    for (int ks = 0; ks < 4; ++ks)
        a[ks] = *(const bf16x8*)&xs[(r0 + m) * F_IN + ks * 32 + q * 8];

    f32x4 acc[4] = {{0,0,0,0},{0,0,0,0},{0,0,0,0},{0,0,0,0}};
    #pragma unroll
    for (int ct = 0; ct < 4; ++ct) {
        #pragma unroll
        for (int ks = 0; ks < 4; ++ks) {
            bf16x8 b = *(const bf16x8*)&Wsh[(ct * 16 + m) * F_IN + ks * 32 + q * 8];
            acc[ct] = __builtin_amdgcn_mfma_f32_16x16x32_bf16(a[ks], b, acc[ct], 0, 0, 0);
        }
    }

    float dv[4];
    #pragma unroll
    for (int reg = 0; reg < 4; ++reg)
        dv[reg] = dinvs[r0 + q * 4 + reg];
    #pragma unroll
    for (int ct = 0; ct < 4; ++ct) {
        #pragma unroll
        for (int reg = 0; reg < 4; ++reg) {
            int grow = row0 + r0 + q * 4 + reg;
            // grow == N writes the zero sentinel row (acc==0 there: A rows >= N staged as 0)
            if (grow <= N)
                g[(size_t)grow * F_OUT + ct * 16 + m] = f2bf(acc[ct][reg] * dv[reg]);
        }
    }
}

// ---- pull aggregation + fused epilogue: wave per dst, branchless MLP-8 loop ----
// Padded lists: every iteration processes 16 edges (8 pair-loads/lane).
// Sentinel src = N gathers the zero row (L1-hot), contributes 0.
__global__ __launch_bounds__(256) void k_pull(
    const unsigned short* __restrict__ g, const int* __restrict__ offsetsP,
    const int* __restrict__ deg, const int* __restrict__ srcsP,
    const float* __restrict__ b_conv, const float* __restrict__ W_lin,
    const float* __restrict__ b_lin, float* __restrict__ out, int N) {
    const int lane   = threadIdx.x & 63;
    const int li     = lane & 31;
    const int half   = lane >> 5;
    const int wave   = (blockIdx.x * blockDim.x + threadIdx.x) >> 6;
    const int nwaves = (gridDim.x * blockDim.x) >> 6;

    const float2 wl = ((const float2*)W_lin)[li];
    const float2 bb = ((const float2*)b_conv)[li];
    const float  bl = b_lin[0];
    const unsigned int* g32 = (const unsigned int*)g;   // row = 32 uints (2 bf16 each)

    for (int i = wave; i < N; i += nwaves) {
        int e0 = __builtin_amdgcn_readfirstlane(offsetsP[i]);
        int dg = __builtin_amdgcn_readfirstlane(deg[i]);
        int e1 = e0 + ((dg + 15) & ~15);

        // self loop: lower half only (upper half adds 0)
        unsigned int us = g32[(size_t)i * 32 + li];
        float a0 = half ? 0.f : bf2f((unsigned short)(us & 0xFFFFu));
        float a1 = half ? 0.f : bf2f((unsigned short)(us >> 16));

        for (int e = e0; e < e1; e += 16) {
            unsigned int u[8];
            #pragma unroll
            for (int t = 0; t < 8; ++t) {
                int sA = srcsP[e + 2 * t];
                int sB = srcsP[e + 2 * t + 1];
                int s  = half ? sB : sA;
                u[t] = g32[(size_t)s * 32 + li];
            }
            #pragma unroll
            for (int t = 0; t < 8; ++t) {
                a0 += bf2f((unsigned short)(u[t] & 0xFFFFu));
                a1 += bf2f((unsigned short)(u[t] >> 16));
            }
        }

        a0 += __shfl_xor(a0, 32, 64);
        a1 += __shfl_xor(a1, 32, 64);

        float dinv = rsqrtf((float)dg + 1.0f);
        float r0 = fmaxf(a0 * dinv + bb.x, 0.f);
        float r1 = fmaxf(a1 * dinv + bb.y, 0.f);
        float t = r0 * wl.x + r1 * wl.y;
        #pragma unroll
        for (int off = 32; off > 0; off >>= 1)
            t += __shfl_down(t, off, 64);
        if (lane == 0)
            out[i] = 1.0f / (1.0f + expf(-(0.5f * t + bl)));   // 0.5: features duplicated across halves
    }
}

extern "C" void kernel_launch(void* const* d_in, const int* in_sizes, int n_in,
                              void* d_out, int out_size, void* d_ws, size_t ws_size,
                              hipStream_t stream) {
    const float* x      = (const float*)d_in[0];
    const int*   ei     = (const int*)d_in[1];
    const float* W_conv = (const float*)d_in[2];
    const float* b_conv = (const float*)d_in[3];
    const float* W_lin  = (const float*)d_in[4];
    const float* b_lin  = (const float*)d_in[5];

    const int N = in_sizes[0] / F_IN;     // 100000
    const int E = in_sizes[1] / 2;        // 1600000
    const int* src = ei;
    const int* dst = ei + E;
    float* out = (float*)d_out;

    const int NBC  = (N + 255) >> 8;            // coarse buckets (391)
    const int NBLK = (E + CHUNK - 1) / CHUNK;   // hist/scatter blocks (313)
    const int S    = NBC * NBLK;                // ~122k
    const int NB1  = (S + 255) / 256;           // scan blocks (479) <= 512

    const int Na = (N + 256) & ~255;
    const int Sa = (S + 256) & ~255;
    const int Ea = (E + 255) & ~255;
    const int EPa = (E + NBC * PADSLACK + 511) & ~255;  // padded srcs size

    // workspace layout (4-byte units), ~34 MB total
    int* M         = (int*)d_ws;                 // [Sa]
    int* tmp       = M + Sa;                     // [Sa]
    int* bsum      = tmp + Sa;                   // [512]
    int* bucketOff = bsum + 512;                 // [MAXB+1]
    int* offsetsP  = bucketOff + (MAXB + 256);   // [Na]
    int* deg       = offsetsP + Na;              // [Na]
    unsigned int* entries = (unsigned int*)(deg + Na);        // [Ea]
    int* srcsP     = (int*)(entries + Ea);       // [EPa]
    unsigned short* g = (unsigned short*)(srcsP + EPa);       // [(N+1)*64] bf16

    k_hist   <<<NBLK, 256, 0, stream>>>(dst, E, M, NBLK, NBC);
    k_scan1  <<<NB1, 256, 0, stream>>>(M, tmp, bsum, S);
    k_scan2  <<<1, 512, 0, stream>>>(bsum, NB1);
    k_scan3  <<<NB1, 256, 0, stream>>>(M, tmp, bsum, bucketOff, S, NBLK, NBC, E);
    k_scatter<<<NBLK, 256, 0, stream>>>(src, dst, E, M, NBLK, NBC, entries);
    k_sort   <<<NBC, 256, 0, stream>>>(entries, bucketOff, offsetsP, deg, srcsP, N);
    k_gemm   <<<(N + 64) / 64, 256, 0, stream>>>(x, W_conv, deg, g, N);
    k_pull   <<<4096, 256, 0, stream>>>(g, offsetsP, deg, srcsP, b_conv, W_lin, b_lin, out, N);
}

// Round 8
// 191.379 us; speedup vs baseline: 5.0847x; 1.0094x over previous
//
#include <hip/hip_runtime.h>
#include <hip/hip_bf16.h>
#include <math.h>

#define F_IN   128
#define F_OUT  64
#define CHUNK  5120          // edges per hist/scatter block
#define MAXB   512           // max coarse buckets
#define PADSLACK 4096        // per-bucket padded-window slack (256 dsts * 15 max pad)

typedef short bf16x8 __attribute__((ext_vector_type(8)));
typedef float f32x4  __attribute__((ext_vector_type(4)));

__device__ __forceinline__ float bf2f(unsigned short u) {
    union { unsigned int i; float f; } c; c.i = ((unsigned int)u) << 16; return c.f;
}
__device__ __forceinline__ unsigned short f2bf(float f) {
    union { float f; unsigned int i; } c; c.f = f;
    unsigned int r = c.i + 0x7FFFu + ((c.i >> 16) & 1u);   // RNE
    return (unsigned short)(r >> 16);
}
__device__ __forceinline__ unsigned int pk2bf(float a, float b) {
    __hip_bfloat162 p = __float22bfloat162_rn(make_float2(a, b));  // v_cvt_pk_bf16_f32
    union { __hip_bfloat162 h; unsigned int u; } c; c.h = p; return c.u;
}
__device__ __forceinline__ float u_lo(unsigned int u) {   // low bf16 -> f32: u<<16
    union { unsigned int i; float f; } c; c.i = u << 16; return c.f;
}
__device__ __forceinline__ float u_hi(unsigned int u) {   // high bf16 -> f32: u & 0xffff0000
    union { unsigned int i; float f; } c; c.i = u & 0xFFFF0000u; return c.f;
}

// ---- pass A: per-block coarse histogram [bucket][block] (LDS only) ----
__global__ __launch_bounds__(256) void k_hist(
    const int* __restrict__ dst, int E, int* __restrict__ M, int NBLK, int NBC) {
    __shared__ int hist[MAXB];
    for (int c = threadIdx.x; c < MAXB; c += 256) hist[c] = 0;
    __syncthreads();
    int e0 = blockIdx.x * CHUNK;
    int e1 = min(E, e0 + CHUNK);
    for (int e = e0 + threadIdx.x; e < e1; e += 256)
        atomicAdd(&hist[dst[e] >> 8], 1);
    __syncthreads();
    for (int c = threadIdx.x; c < NBC; c += 256)
        M[c * NBLK + blockIdx.x] = hist[c];
}

// ---- flat exclusive scan over S = NBC*NBLK elements (3 phases) ----
__global__ void k_scan1(const int* __restrict__ M, int* __restrict__ tmp,
                        int* __restrict__ bsum, int S) {
    __shared__ int sh[256];
    int i = blockIdx.x * 256 + threadIdx.x;
    int v = (i < S) ? M[i] : 0;
    sh[threadIdx.x] = v;
    __syncthreads();
    for (int off = 1; off < 256; off <<= 1) {
        int t = (threadIdx.x >= off) ? sh[threadIdx.x - off] : 0;
        __syncthreads();
        sh[threadIdx.x] += t;
        __syncthreads();
    }
    if (i < S) tmp[i] = sh[threadIdx.x];
    if (threadIdx.x == 255) bsum[blockIdx.x] = sh[255];
}

__global__ void k_scan2(int* __restrict__ bsum, int NB1) {
    __shared__ int sh[512];
    int v = (threadIdx.x < NB1) ? bsum[threadIdx.x] : 0;
    sh[threadIdx.x] = v;
    __syncthreads();
    for (int off = 1; off < 512; off <<= 1) {
        int t = (threadIdx.x >= off) ? sh[threadIdx.x - off] : 0;
        __syncthreads();
        sh[threadIdx.x] += t;
        __syncthreads();
    }
    if (threadIdx.x < NB1) bsum[threadIdx.x] = sh[threadIdx.x] - v;   // exclusive
}

// scan3: M <- exclusive scan; extract bucketOff[bucket]
__global__ void k_scan3(int* __restrict__ M, const int* __restrict__ tmp,
                        const int* __restrict__ bsum, int* __restrict__ bucketOff,
                        int S, int NBLK, int NBC, int E) {
    int i = blockIdx.x * 256 + threadIdx.x;
    if (i < S) {
        int orig = M[i];
        int o = tmp[i] - orig + bsum[blockIdx.x];
        M[i] = o;
        if (i % NBLK == 0) bucketOff[i / NBLK] = o;
    }
    if (i == 0) bucketOff[NBC] = E;
}

// ---- pass B: scatter packed entries (localdst<<24 | src) into coarse buckets ----
__global__ __launch_bounds__(256) void k_scatter(
    const int* __restrict__ src, const int* __restrict__ dst, int E,
    const int* __restrict__ M, int NBLK, int NBC, unsigned int* __restrict__ entries) {
    __shared__ int cur[MAXB];
    for (int c = threadIdx.x; c < NBC; c += 256)
        cur[c] = M[c * NBLK + blockIdx.x];
    __syncthreads();
    int e0 = blockIdx.x * CHUNK;
    int e1 = min(E, e0 + CHUNK);
    for (int e = e0 + threadIdx.x; e < e1; e += 256) {
        int d = dst[e];
        int s = src[e];
        int p = atomicAdd(&cur[d >> 8], 1);
        entries[p] = ((unsigned int)(d & 255) << 24) | (unsigned int)s;
    }
}

// ---- per-bucket counting sort -> PADDED global CSR of BYTE OFFSETS ----
// srcsP[p] = src<<7 (byte offset of g row). Lists padded to multiple of 16
// with sentinel N<<7 (g[N] is a zero row).
__global__ __launch_bounds__(256) void k_sort(
    const unsigned int* __restrict__ entries, const int* __restrict__ bucketOff,
    int* __restrict__ offsetsP, int* __restrict__ deg,
    unsigned int* __restrict__ srcsP, int N) {
    __shared__ int hist[256];
    __shared__ int curs[256];
    const int tid = threadIdx.x;
    const int b = blockIdx.x;
    const int start = bucketOff[b];
    const int end   = bucketOff[b + 1];
    const int startP = start + b * PADSLACK;

    hist[tid] = 0;
    __syncthreads();
    for (int i = start + tid; i < end; i += 256)
        atomicAdd(&hist[entries[i] >> 24], 1);
    __syncthreads();

    int cntv   = hist[tid];
    int padded = (cntv + 15) & ~15;        // 0 stays 0
    curs[tid] = padded;
    __syncthreads();
    for (int off = 1; off < 256; off <<= 1) {
        int t = (tid >= off) ? curs[tid - off] : 0;
        __syncthreads();
        curs[tid] += t;
        __syncthreads();
    }
    int exclP = curs[tid] - padded;
    int d = (b << 8) + tid;
    if (d < N) { offsetsP[d] = startP + exclP; deg[d] = cntv; }
    __syncthreads();
    curs[tid] = startP + exclP;            // scatter cursors
    __syncthreads();

    for (int i = start + tid; i < end; i += 256) {
        unsigned int v = entries[i];
        int p = atomicAdd(&curs[v >> 24], 1);
        srcsP[p] = (v & 0xFFFFFFu) << 7;   // byte offset
    }
    __syncthreads();

    // pad own dst's list with sentinel N<<7
    int padEnd = startP + exclP + padded;
    unsigned int sent = ((unsigned int)N) << 7;
    for (int p = curs[tid]; p < padEnd; ++p)
        srcsP[p] = sent;
}

// ---- MFMA GEMM: g = bf16( (x @ W^T) * rsqrt(deg[row]+1) ); g[N] = zero row ----
__global__ __launch_bounds__(256) void k_gemm(
    const float* __restrict__ x, const float* __restrict__ W,
    const int* __restrict__ deg, unsigned short* __restrict__ g, int N) {
    __shared__ unsigned short xs[64 * F_IN];     // 16 KB
    __shared__ unsigned short Wsh[F_OUT * F_IN]; // 16 KB
    __shared__ float dinvs[64];

    const int tid  = threadIdx.x;
    const int row0 = blockIdx.x * 64;

    {
        const float4* W4 = (const float4*)W;
        #pragma unroll
        for (int t = 0; t < 8; ++t) {
            int idx = t * 256 + tid;
            float4 v = W4[idx];
            uint2 u = make_uint2(pk2bf(v.x, v.y), pk2bf(v.z, v.w));
            *(uint2*)&Wsh[idx * 4] = u;
        }
    }
    {
        const float4* x4 = (const float4*)x;
        #pragma unroll
        for (int t = 0; t < 8; ++t) {
            int idx = t * 256 + tid;
            int r = idx >> 5;
            int grow = row0 + r;
            float4 v = make_float4(0.f, 0.f, 0.f, 0.f);
            if (grow < N) v = x4[(size_t)grow * 32 + (idx & 31)];
            uint2 u = make_uint2(pk2bf(v.x, v.y), pk2bf(v.z, v.w));
            *(uint2*)&xs[idx * 4] = u;
        }
    }
    if (tid < 64) {
        int grow = row0 + tid;
        float dv = 1.0f;
        if (grow < N) dv = rsqrtf((float)deg[grow] + 1.0f);
        dinvs[tid] = dv;
    }
    __syncthreads();

    const int lane = tid & 63;
    const int wave = tid >> 6;
    const int m = lane & 15;
    const int q = lane >> 4;
    const int r0 = wave * 16;

    bf16x8 a[4];
    #pragma unroll
    for (int ks = 0; ks < 4; ++ks)
        a[ks] = *(const bf16x8*)&xs[(r0 + m) * F_IN + ks * 32 + q * 8];

    f32x4 acc[4] = {{0,0,0,0},{0,0,0,0},{0,0,0,0},{0,0,0,0}};
    #pragma unroll
    for (int ct = 0; ct < 4; ++ct) {
        #pragma unroll
        for (int ks = 0; ks < 4; ++ks) {
            bf16x8 b = *(const bf16x8*)&Wsh[(ct * 16 + m) * F_IN + ks * 32 + q * 8];
            acc[ct] = __builtin_amdgcn_mfma_f32_16x16x32_bf16(a[ks], b, acc[ct], 0, 0, 0);
        }
    }

    float dv[4];
    #pragma unroll
    for (int reg = 0; reg < 4; ++reg)
        dv[reg] = dinvs[r0 + q * 4 + reg];
    #pragma unroll
    for (int ct = 0; ct < 4; ++ct) {
        #pragma unroll
        for (int reg = 0; reg < 4; ++reg) {
            int grow = row0 + r0 + q * 4 + reg;
            // grow == N writes the zero sentinel row (acc==0 there)
            if (grow <= N)
                g[(size_t)grow * F_OUT + ct * 16 + m] = f2bf(acc[ct][reg] * dv[reg]);
        }
    }
}

// ---- pull aggregation + fused epilogue: wave per dst, branchless MLP-8 loop ----
// srcsP holds byte offsets (src<<7). Lane's gather addr = g + (off | li<<2).
// Half-wave split: lane reads its half's offsets via sp[2t] (immediate offsets),
// both halves' list reads hit the same cache lines.
__global__ __launch_bounds__(256) void k_pull(
    const unsigned short* __restrict__ g, const int* __restrict__ offsetsP,
    const int* __restrict__ deg, const unsigned int* __restrict__ srcsP,
    const float* __restrict__ b_conv, const float* __restrict__ W_lin,
    const float* __restrict__ b_lin, float* __restrict__ out, int N) {
    const int lane   = threadIdx.x & 63;
    const int li     = lane & 31;
    const int half   = lane >> 5;
    const int wave   = (blockIdx.x * blockDim.x + threadIdx.x) >> 6;
    const int nwaves = (gridDim.x * blockDim.x) >> 6;

    const float2 wl = ((const float2*)W_lin)[li];
    const float2 bb = ((const float2*)b_conv)[li];
    const float  bl = b_lin[0];
    const char* gb = (const char*)g;
    const unsigned int lioff = ((unsigned int)li) << 2;

    for (int i = wave; i < N; i += nwaves) {
        int e0 = __builtin_amdgcn_readfirstlane(offsetsP[i]);
        int dg = __builtin_amdgcn_readfirstlane(deg[i]);
        int niter = (dg + 15) >> 4;

        // self loop: lower half only (upper half adds 0)
        unsigned int us = *(const unsigned int*)(gb + ((((unsigned int)i) << 7) | lioff));
        float2 acc;
        acc.x = half ? 0.f : u_lo(us);
        acc.y = half ? 0.f : u_hi(us);

        const unsigned int* sp = srcsP + e0 + half;   // lane's half-interleaved list
        for (int it = 0; it < niter; ++it) {
            unsigned int off[8];
            #pragma unroll
            for (int t = 0; t < 8; ++t)
                off[t] = sp[2 * t];                   // immediate offsets 0,8,16,...
            unsigned int u[8];
            #pragma unroll
            for (int t = 0; t < 8; ++t)
                u[t] = *(const unsigned int*)(gb + (size_t)(off[t] | lioff));
            #pragma unroll
            for (int t = 0; t < 8; ++t) {
                acc.x += u_lo(u[t]);
                acc.y += u_hi(u[t]);
            }
            sp += 16;
        }

        acc.x += __shfl_xor(acc.x, 32, 64);
        acc.y += __shfl_xor(acc.y, 32, 64);

        float dinv = rsqrtf((float)dg + 1.0f);
        float r0 = fmaxf(acc.x * dinv + bb.x, 0.f);
        float r1 = fmaxf(acc.y * dinv + bb.y, 0.f);
        float t = r0 * wl.x + r1 * wl.y;
        #pragma unroll
        for (int off = 32; off > 0; off >>= 1)
            t += __shfl_down(t, off, 64);
        if (lane == 0)
            out[i] = 1.0f / (1.0f + expf(-(0.5f * t + bl)));   // 0.5: features duplicated across halves
    }
}

extern "C" void kernel_launch(void* const* d_in, const int* in_sizes, int n_in,
                              void* d_out, int out_size, void* d_ws, size_t ws_size,
                              hipStream_t stream) {
    const float* x      = (const float*)d_in[0];
    const int*   ei     = (const int*)d_in[1];
    const float* W_conv = (const float*)d_in[2];
    const float* b_conv = (const float*)d_in[3];
    const float* W_lin  = (const float*)d_in[4];
    const float* b_lin  = (const float*)d_in[5];

    const int N = in_sizes[0] / F_IN;     // 100000
    const int E = in_sizes[1] / 2;        // 1600000
    const int* src = ei;
    const int* dst = ei + E;
    float* out = (float*)d_out;

    const int NBC  = (N + 255) >> 8;            // coarse buckets (391)
    const int NBLK = (E + CHUNK - 1) / CHUNK;   // hist/scatter blocks (313)
    const int S    = NBC * NBLK;                // ~122k
    const int NB1  = (S + 255) / 256;           // scan blocks (479) <= 512

    const int Na = (N + 256) & ~255;
    const int Sa = (S + 256) & ~255;
    const int Ea = (E + 255) & ~255;
    const int EPa = (E + NBC * PADSLACK + 511) & ~255;  // padded srcs size

    // workspace layout (4-byte units), ~34 MB total
    int* M         = (int*)d_ws;                 // [Sa]
    int* tmp       = M + Sa;                     // [Sa]
    int* bsum      = tmp + Sa;                   // [512]
    int* bucketOff = bsum + 512;                 // [MAXB+1]
    int* offsetsP  = bucketOff + (MAXB + 256);   // [Na]
    int* deg       = offsetsP + Na;              // [Na]
    unsigned int* entries = (unsigned int*)(deg + Na);        // [Ea]
    unsigned int* srcsP   = (unsigned int*)(entries + Ea);    // [EPa]
    unsigned short* g = (unsigned short*)(srcsP + EPa);       // [(N+1)*64] bf16

    k_hist   <<<NBLK, 256, 0, stream>>>(dst, E, M, NBLK, NBC);
    k_scan1  <<<NB1, 256, 0, stream>>>(M, tmp, bsum, S);
    k_scan2  <<<1, 512, 0, stream>>>(bsum, NB1);
    k_scan3  <<<NB1, 256, 0, stream>>>(M, tmp, bsum, bucketOff, S, NBLK, NBC, E);
    k_scatter<<<NBLK, 256, 0, stream>>>(src, dst, E, M, NBLK, NBC, entries);
    k_sort   <<<NBC, 256, 0, stream>>>(entries, bucketOff, offsetsP, deg, srcsP, N);
    k_gemm   <<<(N + 64) / 64, 256, 0, stream>>>(x, W_conv, deg, g, N);
    k_pull   <<<4096, 256, 0, stream>>>(g, offsetsP, deg, srcsP, b_conv, W_lin, b_lin, out, N);
}